// Round 3
// baseline (197.351 us; speedup 1.0000x reference)
//
#include <hip/hip_runtime.h>
#include <stdint.h>
#include <stddef.h>

typedef _Float16 h2 __attribute__((ext_vector_type(2)));
typedef _Float16 h8 __attribute__((ext_vector_type(8)));
typedef float f4 __attribute__((ext_vector_type(4)));

union Hfrag { h2 p[4]; h8 v; };

// ---------------- workspace layout (bytes) ----------------
// pmin/pmax (K1 partials) are dead after K2; Bt (built in K3) overlays them.
#define WS_PMIN   0               // f32 [512][256] = 512 KB
#define WS_PMAX   524288          // f32 [512][256] = 512 KB
#define WS_BT     0               // f16 [80 ks][2 half][128 o][32 kk] = 1,310,720 B
#define WS_SMALL  1310720
#define WS_BSC    (WS_SMALL + 0)
#define WS_BSH    (WS_SMALL + 1024)
#define WS_SSC    (WS_SMALL + 2048)
#define WS_SSH    (WS_SMALL + 3072)
#define WS_MINH   (WS_SMALL + 4096)   // f16[256]
#define WS_SCH    (WS_SMALL + 4608)   // f16[256] 1/range
#define WS_RGH    (WS_SMALL + 5120)   // f16[256] range

// ---------------- K1: per-feature min/max partials ----------------
__global__ __launch_bounds__(256) void kan_minmax(const float* __restrict__ x,
                                                  float* __restrict__ pmin,
                                                  float* __restrict__ pmax) {
  __shared__ f4 smn[4][64], smx[4][64];
  const int b = blockIdx.x, t = threadIdx.x;
  const int fq = t & 63, rg = t >> 6;
  const float* p = x + (size_t)b * 64 * 256 + (size_t)rg * 16 * 256 + fq * 4;
  f4 mn = (f4)(3.402823466e38f), mx = (f4)(-3.402823466e38f);
#pragma unroll
  for (int j = 0; j < 16; ++j) {
    f4 v = *(const f4*)(p + (size_t)j * 256);
    mn = __builtin_elementwise_min(mn, v);
    mx = __builtin_elementwise_max(mx, v);
  }
  smn[rg][fq] = mn; smx[rg][fq] = mx;
  __syncthreads();
  if (rg == 0) {
#pragma unroll
    for (int g = 1; g < 4; ++g) {
      mn = __builtin_elementwise_min(mn, smn[g][fq]);
      mx = __builtin_elementwise_max(mx, smx[g][fq]);
    }
    *(f4*)(pmin + (size_t)b * 256 + fq * 4) = mn;
    *(f4*)(pmax + (size_t)b * 256 + fq * 4) = mx;
  }
}

// ---------------- K2: finalize minmax + BN constants (f32 + f16 tables) ----------------
__global__ __launch_bounds__(256) void kan_finalize(
    const float* __restrict__ pmin, const float* __restrict__ pmax,
    const float* __restrict__ g1, const float* __restrict__ b1,
    const float* __restrict__ m1, const float* __restrict__ v1,
    const float* __restrict__ g2, const float* __restrict__ b2,
    const float* __restrict__ m2, const float* __restrict__ v2,
    float* __restrict__ bscv, float* __restrict__ bshv,
    float* __restrict__ sscv, float* __restrict__ sshv,
    _Float16* __restrict__ minh, _Float16* __restrict__ sch,
    _Float16* __restrict__ rgh) {
  __shared__ float smn[4][64], smx[4][64];
  const int t = threadIdx.x;
  const int ol = t & 63, pg = t >> 6;
  const int o = blockIdx.x * 64 + ol;
  float mn = 3.402823466e38f, mx = -3.402823466e38f;
  for (int p = pg * 128; p < pg * 128 + 128; ++p) {
    mn = fminf(mn, pmin[(size_t)p * 256 + o]);
    mx = fmaxf(mx, pmax[(size_t)p * 256 + o]);
  }
  smn[pg][ol] = mn; smx[pg][ol] = mx;
  __syncthreads();
  if (pg == 0) {
#pragma unroll
    for (int g = 1; g < 4; ++g) {
      mn = fminf(mn, smn[g][ol]);
      mx = fmaxf(mx, smx[g][ol]);
    }
    const float range = mx - mn + 1e-7f;
    minh[o] = (_Float16)mn;
    sch[o]  = (_Float16)(1.0f / range);
    rgh[o]  = (_Float16)range;
    const float bs = g1[o] / sqrtf(v1[o] + 1e-3f);
    bscv[o] = bs;
    bshv[o] = b1[o] - m1[o] * bs;
    const float ss = g2[o] / sqrtf(v2[o] + 1e-3f);
    sscv[o] = ss;
    sshv[o] = b2[o] - m2[o] * ss;
  }
}

// ---------------- K3: build f16 weight matrix Bt ----------------
// Bt flat index f = ((ks*2 + half)*128 + o)*32 + kk   (2B halves)
// ks<72: spline, knot k = ks>>3, i = (ks&7)*32+kk; val = sw[o,i,k]*ss[o,i]
//        (knot 0 chunks ks 0..7 are never read: basis_0 == 0 for xn in [0,1])
// ks>=72: base, i = (ks-72)*32+kk; val = Wb[i,o]   (A will be f16(x))
__global__ __launch_bounds__(256) void kan_buildw(
    const float* __restrict__ spline_w, const float* __restrict__ spline_s,
    const float* __restrict__ base_w, _Float16* __restrict__ Bt) {
  const int gid = blockIdx.x * 256 + threadIdx.x;  // 640 blocks
  const int f = gid * 4;
  const int ks = f >> 13;
  const int rem = f & 8191;
  const int half = rem >> 12;
  const int rem2 = rem & 4095;
  const int o = rem2 >> 5;
  const int kk = rem2 & 31;
  const int og = half * 128 + o;
  float v[4];
  if (ks < 72) {
    const int k = ks >> 3;
    const int i0 = ((ks & 7) << 5) + kk;
#pragma unroll
    for (int j = 0; j < 4; ++j) {
      const int i = i0 + j;
      v[j] = spline_w[(size_t)(og * 256 + i) * 9 + k] * spline_s[og * 256 + i];
    }
  } else {
    const int i0 = (ks - 72) * 32 + kk;
#pragma unroll
    for (int j = 0; j < 4; ++j) {
      const int i = i0 + j;
      v[j] = base_w[(size_t)i * 256 + og];
    }
  }
  union { _Float16 h[4]; uint2 u; } pk;
#pragma unroll
  for (int j = 0; j < 4; ++j) pk.h[j] = (_Float16)v[j];
  *(uint2*)(Bt + f) = pk.u;
}

// ---------------- K4: fused dual GEMM + BN + SiLU ----------------
// 64x128 output tile, 4 waves (2x2: 32 rows x 64 cols each), m=2, n=4.
// Grid 1024 -> 4 blocks/CU (4 waves/SIMD) for latency hiding. No LDS, no
// barriers; B fragments straight from L2-resident Bt. A path fully f16.
__global__ __launch_bounds__(256, 4) void kan_gemm(
    const float* __restrict__ x, const _Float16* __restrict__ Bt,
    const _Float16* __restrict__ minh, const _Float16* __restrict__ sch,
    const _Float16* __restrict__ rgh,
    const float* __restrict__ bscv, const float* __restrict__ bshv,
    const float* __restrict__ sscv, const float* __restrict__ sshv,
    float* __restrict__ out) {
  const int tid = threadIdx.x;
  const int lane = tid & 63;
  const int wv = tid >> 6;
  const int wm = wv >> 1, wn = wv & 1;
  const int lr = lane & 15, lg = lane >> 4;
  // XCD-aware swizzle: bid and bid+8 (same mt, both nt) land on the same XCD
  const int j = blockIdx.x & 15, g = blockIdx.x >> 4;
  const int mt = g * 8 + (j & 7);   // 0..511 (64-row tiles)
  const int nt = j >> 3;            // 0..1

  const int rowA = mt * 64 + wm * 32 + lr;   // + 16*m
  const int colB = wn * 64 + lr;             // local out col; + 16*n, global +nt*128

  f4 accS[2][4], accB[2][4];
#pragma unroll
  for (int m = 0; m < 2; ++m)
#pragma unroll
    for (int n = 0; n < 4; ++n) { accS[m][n] = (f4)0.0f; accB[m][n] = (f4)0.0f; }

  // per-lane B base: chunk ks at + ks*16384; fragment n at + n*1024
  const char* btbase = (const char*)Bt + (size_t)nt * 8192 + (size_t)colB * 64 + (size_t)lg * 16;

#pragma unroll 1
  for (int ic = 0; ic < 8; ++ic) {
    const int ib = ic * 32 + lg * 8;
    Hfrag mh, sh, rh;
    mh.v = *(const h8*)(minh + ib);
    sh.v = *(const h8*)(sch + ib);
    rh.v = *(const h8*)(rgh + ib);
    // xn = (f16(x) - min) * (1/range), packed pairs in A-fragment layout
    Hfrag xn[2];
#pragma unroll
    for (int m = 0; m < 2; ++m) {
      const float* px = x + (size_t)(rowA + m * 16) * 256 + ib;
      f4 a = *(const f4*)px;
      f4 b = *(const f4*)(px + 4);
      h2 h0; h0[0] = (_Float16)a.x; h0[1] = (_Float16)a.y;
      h2 h1; h1[0] = (_Float16)a.z; h1[1] = (_Float16)a.w;
      h2 h2v; h2v[0] = (_Float16)b.x; h2v[1] = (_Float16)b.y;
      h2 h3; h3[0] = (_Float16)b.z; h3[1] = (_Float16)b.w;
      xn[m].p[0] = (h0 - mh.p[0]) * sh.p[0];
      xn[m].p[1] = (h1 - mh.p[1]) * sh.p[1];
      xn[m].p[2] = (h2v - mh.p[2]) * sh.p[2];
      xn[m].p[3] = (h3 - mh.p[3]) * sh.p[3];
    }
#pragma unroll
    for (int it = 0; it < 9; ++it) {   // it 0..7: knots 1..8 ; it 8: base GEMM step
      const int cks = (it < 8) ? ((it + 1) * 8 + ic) : (72 + ic);
      const char* bp = btbase + (size_t)cks * 16384;
      Hfrag bf[4];
#pragma unroll
      for (int n = 0; n < 4; ++n)
        bf[n].v = *(const h8*)(bp + n * 1024);
      Hfrag af[2];
      if (it < 8) {
        const float t = -1.0f + 0.25f * (float)(it + 1);
        const _Float16 c1 = (_Float16)(1.0f + t);
        const _Float16 c2 = (_Float16)(1.0f - t);
        h2 hc1; hc1[0] = c1; hc1[1] = c1;
        h2 hc2; hc2[0] = c2; hc2[1] = c2;
        h2 hz;  hz[0] = (_Float16)0.0f; hz[1] = (_Float16)0.0f;
#pragma unroll
        for (int m = 0; m < 2; ++m) {
#pragma unroll
          for (int q = 0; q < 4; ++q) {
            h2 xv = xn[m].p[q];
            h2 u = hc1 - xv;              // 1 - (xn - t)
            h2 w = hc2 + xv;              // 1 + (xn - t)
            af[m].p[q] = __builtin_elementwise_max(__builtin_elementwise_min(u, w), hz);
          }
        }
#pragma unroll
        for (int m = 0; m < 2; ++m)
#pragma unroll
          for (int n = 0; n < 4; ++n)
            accS[m][n] = __builtin_amdgcn_mfma_f32_16x16x32_f16(af[m].v, bf[n].v, accS[m][n], 0, 0, 0);
      } else {
        // base step: A = f16(x) reconstructed as xn*range + min (pk_fma)
#pragma unroll
        for (int m = 0; m < 2; ++m) {
#pragma unroll
          for (int q = 0; q < 4; ++q)
            af[m].p[q] = xn[m].p[q] * rh.p[q] + mh.p[q];
        }
#pragma unroll
        for (int m = 0; m < 2; ++m)
#pragma unroll
          for (int n = 0; n < 4; ++n)
            accB[m][n] = __builtin_amdgcn_mfma_f32_16x16x32_f16(af[m].v, bf[n].v, accB[m][n], 0, 0, 0);
      }
    }
  }

  // epilogue: out = silu(accB*bs + bsh) + accS*ss + ssh   (C layout: col=l&15, row=(l>>4)*4+r)
#pragma unroll
  for (int n = 0; n < 4; ++n) {
    const int col = nt * 128 + wn * 64 + n * 16 + lr;
    const float vbs = bscv[col], vbh = bshv[col];
    const float vss = sscv[col], vsh = sshv[col];
#pragma unroll
    for (int m = 0; m < 2; ++m) {
      const int row0 = mt * 64 + wm * 32 + m * 16 + lg * 4;
#pragma unroll
      for (int r = 0; r < 4; ++r) {
        const float zb = accB[m][n][r] * vbs + vbh;
        const float si = zb / (1.0f + __expf(-zb));
        const float val = si + accS[m][n][r] * vss + vsh;
        out[(size_t)(row0 + r) * 256 + col] = val;
      }
    }
  }
}

extern "C" void kernel_launch(void* const* d_in, const int* in_sizes, int n_in,
                              void* d_out, int out_size, void* d_ws, size_t ws_size,
                              hipStream_t stream) {
  const float* x        = (const float*)d_in[0];
  const float* base_w   = (const float*)d_in[1];
  const float* spline_w = (const float*)d_in[2];
  const float* spline_s = (const float*)d_in[3];
  const float* g1 = (const float*)d_in[4];
  const float* b1 = (const float*)d_in[5];
  const float* m1 = (const float*)d_in[6];
  const float* v1 = (const float*)d_in[7];
  const float* g2 = (const float*)d_in[8];
  const float* b2 = (const float*)d_in[9];
  const float* m2 = (const float*)d_in[10];
  const float* v2 = (const float*)d_in[11];
  float* out = (float*)d_out;
  char* ws = (char*)d_ws;

  float* pmin   = (float*)(ws + WS_PMIN);
  float* pmax   = (float*)(ws + WS_PMAX);
  _Float16* Bt  = (_Float16*)(ws + WS_BT);
  float* bscv   = (float*)(ws + WS_BSC);
  float* bshv   = (float*)(ws + WS_BSH);
  float* sscv   = (float*)(ws + WS_SSC);
  float* sshv   = (float*)(ws + WS_SSH);
  _Float16* minh = (_Float16*)(ws + WS_MINH);
  _Float16* sch  = (_Float16*)(ws + WS_SCH);
  _Float16* rgh  = (_Float16*)(ws + WS_RGH);

  kan_minmax<<<512, 256, 0, stream>>>(x, pmin, pmax);
  kan_finalize<<<4, 256, 0, stream>>>(pmin, pmax, g1, b1, m1, v1, g2, b2, m2, v2,
                                      bscv, bshv, sscv, sshv, minh, sch, rgh);
  kan_buildw<<<640, 256, 0, stream>>>(spline_w, spline_s, base_w, Bt);
  kan_gemm<<<1024, 256, 0, stream>>>(x, Bt, minh, sch, rgh,
                                     bscv, bshv, sscv, sshv, out);
}